// Round 1
// 1019.316 us; speedup vs baseline: 1.4220x; 1.4220x over previous
//
#include <hip/hip_runtime.h>
#include <cstddef>

// ---------- types ----------
typedef _Float16 f16x8 __attribute__((ext_vector_type(8)));
typedef _Float16 f16x4 __attribute__((ext_vector_type(4)));
typedef short    s16x8 __attribute__((ext_vector_type(8)));
typedef short    s16x4 __attribute__((ext_vector_type(4)));
typedef float    f32x4 __attribute__((ext_vector_type(4)));

#define MFMA_F16(a, b, c) __builtin_amdgcn_mfma_f32_16x16x32_f16((a), (b), (c), 0, 0, 0)

#if __has_builtin(__builtin_amdgcn_rcpf)
__device__ __forceinline__ float fast_rcp(float x) { return __builtin_amdgcn_rcpf(x); }
#else
__device__ __forceinline__ float fast_rcp(float x) { return 1.f / x; }
#endif

__device__ __forceinline__ f16x8 ld8(const short* p) {
  return __builtin_bit_cast(f16x8, *(const s16x8*)p);
}
__device__ __forceinline__ f16x4 ld4(const short* p) {
  return __builtin_bit_cast(f16x4, *(const s16x4*)p);
}

// Barrier WITHOUT the vmcnt(0) drain: LDS ordering only (lgkmcnt), so
// cross-step global prefetches and hseq stores stay in flight (T3/T4 idea).
__device__ __forceinline__ void barrier_nodrain() {
  asm volatile("s_waitcnt lgkmcnt(0)" ::: "memory");
  __builtin_amdgcn_s_barrier();
  asm volatile("" ::: "memory");
}

// ---------- fp32 -> fp16 casts, one launch ----------
struct CastDesc { const float* src; short* dst; int n; };
struct CastArgs { CastDesc d[7]; };

__global__ void cast_many(CastArgs a) {
  const int tid = blockIdx.x * blockDim.x + threadIdx.x;
  const int stride = gridDim.x * blockDim.x;
#pragma unroll
  for (int j = 0; j < 7; j++) {
    const float* __restrict__ s = a.d[j].src;
    short* __restrict__ o = a.d[j].dst;
    const int n = a.d[j].n;
    for (int i = tid; i < n; i += stride)
      o[i] = __builtin_bit_cast(short, (_Float16)s[i]);
  }
}

// ---------- input-projection GEMM (t-parallel, high occupancy) ----------
// xg[bt][t-t0][c][bm] = sum_k A[(bt*16+bm), t, k] * W[c][k] + bias[c], fp16.
// Tile-major output so the recurrent kernel reads one b64 per (gate, jt).
// Grid: (B/16) x (TC/16). Per wave: JT 16-col tiles, weights register-resident.
template <int K, int NO, int NW, int JT>
__global__ __launch_bounds__(NW * 64, 2)
void xg_gemm(const short* __restrict__ A,    // [B, T, K] fp16
             const short* __restrict__ W,    // [NO, K] fp16
             const float* __restrict__ bias, // [NO] fp32 (b_ih)
             short* __restrict__ xg,         // [B/16][TC][NO][16] fp16
             int t0, int TC) {
  static_assert(NW * 16 * JT == NO, "wave tiling must cover NO");
  constexpr int T = 256;
  constexpr int TT = 16;     // timesteps per workgroup
  constexpr int KC = K / 32;
  const int lane = threadIdx.x & 63;
  const int wid  = threadIdx.x >> 6;
  const int p = lane & 15, q = lane >> 4;
  const int bt = blockIdx.x;
  const int tbeg = t0 + blockIdx.y * TT;
  const int j0 = wid * 16 * JT;

  f16x8 wb[JT][KC];
  float bc[JT];
#pragma unroll
  for (int jt = 0; jt < JT; jt++) {
    const int col = j0 + jt * 16 + p;
    bc[jt] = bias[col];
#pragma unroll
    for (int kc = 0; kc < KC; kc++)
      wb[jt][kc] = ld8(W + (size_t)col * K + kc * 32 + q * 8);
  }

  const short* arow = A + ((size_t)(bt * 16 + p) * T + tbeg) * K + q * 8;
  short* outb = xg + ((size_t)bt * TC + (tbeg - t0)) * NO * 16;

  f16x8 a0[KC], a1[KC];
#pragma unroll
  for (int kc = 0; kc < KC; kc++) a0[kc] = ld8(arow + kc * 32);

  auto step = [&](int ti, f16x8 (&ac)[KC], f16x8 (&anx)[KC], bool pf) {
    if (pf) {  // prefetch next timestep's A fragments (in flight across MFMAs)
#pragma unroll
      for (int kc = 0; kc < KC; kc++)
        anx[kc] = ld8(arow + (size_t)(ti + 1) * K + kc * 32);
    }
    f32x4 acc[JT];
#pragma unroll
    for (int jt = 0; jt < JT; jt++)
      acc[jt] = f32x4{bc[jt], bc[jt], bc[jt], bc[jt]};
#pragma unroll
    for (int kc = 0; kc < KC; kc++)
#pragma unroll
      for (int jt = 0; jt < JT; jt++)
        acc[jt] = MFMA_F16(ac[kc], wb[jt][kc], acc[jt]);
    short* ob = outb + (size_t)ti * NO * 16;
#pragma unroll
    for (int jt = 0; jt < JT; jt++) {  // C/D: col = lane&15, row = q*4+r
      const int col = j0 + jt * 16 + p;
      s16x4 v;
#pragma unroll
      for (int r = 0; r < 4; r++)
        v[r] = __builtin_bit_cast(short, (_Float16)acc[jt][r]);
      *(s16x4*)&ob[col * 16 + q * 4] = v;
    }
  };

#pragma unroll 1
  for (int ti = 0; ti < TT; ti += 2) {  // static double-buffer rotation
    step(ti, a0, a1, true);
    step(ti + 1, a1, a0, ti + 2 < TT);
  }
}

// ---------- recurrence-only GRU kernel ----------
// Whh r,z (and n if !NLDS) register-resident; n-gate in LDS for H=256.
// xg read with XD-deep prefetch that survives the no-drain barrier.
// hstate carries (fp32) h across chunks; SEQ stores [B,T,H] fp16 for next layer.
template <int H, int NW, int JT, bool NLDS, bool SEQ, int XD>
__global__ __launch_bounds__(NW * 64, (NW / 4 >= 2) ? 2 : 1)
void gru_rec(const short* __restrict__ xg,   // [B/16][TC][3H][16] fp16 (x·Wih^T + b_ih)
             const short* __restrict__ Whh,  // [3H, H] fp16
             const float* __restrict__ bhh,  // [3H]
             short* __restrict__ hseq,       // [B,T,H] fp16 if SEQ
             float* __restrict__ hstate,     // [B,H] fp32 chunk-carry / final h
             int t0, int t1, int TC) {
  static_assert(NW * 16 * JT == H, "wave tiling must cover H");
  static_assert(XD == 2 || XD == 4, "XD even for static parity");
  constexpr int T = 256;
  constexpr int KS = H / 32;
  constexpr int HP = H + 8;   // stride 33*16B per row: uniform bank-group spread
  constexpr int NO = 3 * H;

  extern __shared__ __align__(16) short smem[];
  short* wn = smem;                          // [H][HP] if NLDS
  short* hb = smem + (NLDS ? H * HP : 0);    // [2][16][HP]

  const int tid  = threadIdx.x;
  const int lane = tid & 63;
  const int wid  = tid >> 6;
  const int p = lane & 15, q = lane >> 4;
  const int b0 = blockIdx.x * 16;
  const int j0 = wid * 16 * JT;

  if constexpr (NLDS) {  // stage n-gate rows of Whh into LDS (one-time)
    constexpr int KV = H / 8;
    for (int i = tid; i < H * KV; i += NW * 64) {
      const int row = i / KV, kc = i - row * KV;
      *(s16x8*)&wn[row * HP + kc * 8] =
          *(const s16x8*)&Whh[(size_t)(2 * H + row) * H + kc * 8];
    }
  }
  // init current h buffer (local step 0 -> buffer 0)
  if (t0 == 0) {
    for (int i = tid; i < 16 * HP; i += NW * 64) hb[i] = 0;
  } else {
    for (int i = tid; i < 16 * H; i += NW * 64) {
      const int row = i / H, col = i - row * H;
      hb[row * HP + col] =
          __builtin_bit_cast(short, (_Float16)hstate[(size_t)(b0 + row) * H + col]);
    }
  }

  // register-resident Whh fragments
  f16x8 wr[JT][NLDS ? 2 : 3][KS];
#pragma unroll
  for (int jt = 0; jt < JT; jt++) {
    const int col = j0 + jt * 16 + p;
#pragma unroll
    for (int g = 0; g < (NLDS ? 2 : 3); g++)
#pragma unroll
      for (int k = 0; k < KS; k++)
        wr[jt][g][k] = ld8(Whh + (size_t)(g * H + col) * H + k * 32 + q * 8);
  }
  float bhr[JT], bhz[JT], bhn[JT];
  int wrow[JT];
#pragma unroll
  for (int jt = 0; jt < JT; jt++) {
    const int col = j0 + jt * 16 + p;
    wrow[jt] = col;
    bhr[jt] = bhh[col];
    bhz[jt] = bhh[H + col];
    bhn[jt] = bhh[2 * H + col];
  }

  float hprev[JT][4];
#pragma unroll
  for (int jt = 0; jt < JT; jt++)
#pragma unroll
    for (int r = 0; r < 4; r++)
      hprev[jt][r] = (t0 == 0) ? 0.f
                   : hstate[(size_t)(b0 + q * 4 + r) * H + (j0 + jt * 16 + p)];

  // xg per-lane addressing (tile-major)
  const size_t sbase = (size_t)blockIdx.x * TC * NO * 16;
  int loff[JT][3];
#pragma unroll
  for (int jt = 0; jt < JT; jt++)
#pragma unroll
    for (int g = 0; g < 3; g++)
      loff[jt][g] = (g * H + j0 + jt * 16 + p) * 16 + q * 4;

  // prime XD steps of xg
  f16x4 xb[XD][JT][3];
#pragma unroll
  for (int u = 0; u < XD; u++)
#pragma unroll
    for (int jt = 0; jt < JT; jt++)
#pragma unroll
      for (int g = 0; g < 3; g++)
        xb[u][jt][g] = ld4(xg + sbase + (size_t)u * NO * 16 + loff[jt][g]);

  __syncthreads();

  const int steps = t1 - t0;
#pragma unroll 1
  for (int sb = 0; sb < steps; sb += XD) {
#pragma unroll
    for (int u = 0; u < XD; u++) {          // XD even => parity is compile-time
      const int s = sb + u;
      const int t = t0 + s;
      short* hbc = hb + (u & 1) * 16 * HP;
      short* hbn = hb + ((u & 1) ^ 1) * 16 * HP;

      f32x4 ar[JT], az[JT], an[JT];
#pragma unroll
      for (int jt = 0; jt < JT; jt++) {     // acc init = xg (r,z) incl. b_ih
#pragma unroll
        for (int r = 0; r < 4; r++) {
          ar[jt][r] = (float)xb[u][jt][0][r];
          az[jt][r] = (float)xb[u][jt][1][r];
        }
        an[jt] = f32x4{0.f, 0.f, 0.f, 0.f};
      }
      // recurrence: k outer, h fragment shared across jt
#pragma unroll
      for (int k = 0; k < KS; k++) {
        const f16x8 ahk = ld8(&hbc[p * HP + k * 32 + q * 8]);
#pragma unroll
        for (int jt = 0; jt < JT; jt++) {
          ar[jt] = MFMA_F16(ahk, wr[jt][0][k], ar[jt]);
          az[jt] = MFMA_F16(ahk, wr[jt][1][k], az[jt]);
          if constexpr (NLDS) {
            const f16x8 wnk = ld8(&wn[wrow[jt] * HP + k * 32 + q * 8]);
            an[jt] = MFMA_F16(ahk, wnk, an[jt]);
          } else {
            an[jt] = MFMA_F16(ahk, wr[jt][2][k], an[jt]);
          }
        }
      }
      // epilogue: C/D layout col = lane&15, row = q*4+r
#pragma unroll
      for (int jt = 0; jt < JT; jt++) {
        const int col = j0 + jt * 16 + p;
#pragma unroll
        for (int r = 0; r < 4; r++) {
          const int bm = q * 4 + r;
          const float rpre = ar[jt][r] + bhr[jt];
          const float zpre = az[jt][r] + bhz[jt];
          const float rg = fast_rcp(1.f + __expf(-rpre));
          const float zg = fast_rcp(1.f + __expf(-zpre));
          const float xnv = (float)xb[u][jt][2][r];  // xn + b_ihn
          const float narg = xnv + rg * (an[jt][r] + bhn[jt]);
          const float e2 = __expf(2.f * narg);
          const float ng = 1.f - 2.f * fast_rcp(e2 + 1.f);  // tanh
          const float hnew = (1.f - zg) * ng + zg * hprev[jt][r];
          hprev[jt][r] = hnew;
          const _Float16 hf = (_Float16)hnew;
          hbn[bm * HP + col] = __builtin_bit_cast(short, hf);
          if constexpr (SEQ)
            hseq[((size_t)(b0 + bm) * T + t) * H + col] = __builtin_bit_cast(short, hf);
        }
      }
      if (t == t1 - 1) {  // chunk-carry / final state (fp32, exact)
#pragma unroll
        for (int jt = 0; jt < JT; jt++)
#pragma unroll
          for (int r = 0; r < 4; r++)
            hstate[(size_t)(b0 + q * 4 + r) * H + (j0 + jt * 16 + p)] = hprev[jt][r];
      }
      // refill xb[u] for step s+XD (chunk buffer has XD-row pad for overrun)
      {
        const size_t s2 = sbase + (size_t)(s + XD) * NO * 16;
#pragma unroll
        for (int jt = 0; jt < JT; jt++)
#pragma unroll
          for (int g = 0; g < 3; g++)
            xb[u][jt][g] = ld4(xg + s2 + loff[jt][g]);
      }
      barrier_nodrain();  // prefetches + hseq stores stay in flight
    }
  }
}

// ---------- dense head ----------
__global__ void dense_kernel(const float* __restrict__ hl, const float* __restrict__ Wd,
                             const float* __restrict__ bd, float* __restrict__ out) {
  const int b = blockIdx.x * 64 + threadIdx.x;
  float a = bd[0];
#pragma unroll
  for (int k = 0; k < 64; k++) a = fmaf(hl[b * 64 + k], Wd[k], a);
  out[b] = a;
}

// ---------- host ----------
extern "C" void kernel_launch(void* const* d_in, const int* in_sizes, int n_in,
                              void* d_out, int out_size, void* d_ws, size_t ws_size,
                              hipStream_t stream) {
  constexpr int B = 512, T = 256, F = 64;
  constexpr int H1 = 256, H2 = 128, H3 = 64;
  constexpr int M = B * T;

  const float* x     = (const float*)d_in[0];
  const float* W_ih1 = (const float*)d_in[1];
  const float* W_hh1 = (const float*)d_in[2];
  const float* b_ih1 = (const float*)d_in[3];
  const float* b_hh1 = (const float*)d_in[4];
  const float* W_ih2 = (const float*)d_in[5];
  const float* W_hh2 = (const float*)d_in[6];
  const float* b_ih2 = (const float*)d_in[7];
  const float* b_hh2 = (const float*)d_in[8];
  const float* W_ih3 = (const float*)d_in[9];
  const float* W_hh3 = (const float*)d_in[10];
  const float* b_ih3 = (const float*)d_in[11];
  const float* b_hh3 = (const float*)d_in[12];
  const float* W_d   = (const float*)d_in[13];
  const float* b_d   = (const float*)d_in[14];
  float* out = (float*)d_out;

  char* ws = (char*)d_ws;
  size_t off = 0;
  auto alloc = [&](size_t bytes) -> char* {
    char* pp = ws + off;
    off = (off + bytes + 255) & ~(size_t)255;
    return pp;
  };

  const int nx    = M * F;
  const int nwih1 = 3 * H1 * F,  nwhh1 = 3 * H1 * H1;
  const int nwih2 = 3 * H2 * H1, nwhh2 = 3 * H2 * H2;
  const int nwih3 = 3 * H3 * H2, nwhh3 = 3 * H3 * H3;

  short* xh     = (short*)alloc((size_t)nx * 2);
  short* wih1   = (short*)alloc((size_t)nwih1 * 2);
  short* whh1   = (short*)alloc((size_t)nwhh1 * 2);
  short* wih2   = (short*)alloc((size_t)nwih2 * 2);
  short* whh2   = (short*)alloc((size_t)nwhh2 * 2);
  short* wih3   = (short*)alloc((size_t)nwih3 * 2);
  short* whh3   = (short*)alloc((size_t)nwhh3 * 2);
  short* h1     = (short*)alloc((size_t)M * H1 * 2);
  short* h2     = (short*)alloc((size_t)M * H2 * 2);
  float* hstate = (float*)alloc((size_t)B * H1 * 4);  // reused per layer (stride H_i)
  short* xgbuf  = (short*)(ws + off);
  const size_t avail = (ws_size > off) ? (ws_size - off) : 0;
  (void)n_in; (void)in_sizes; (void)out_size;

  CastArgs ca;
  ca.d[0] = {x, xh, nx};
  ca.d[1] = {W_ih1, wih1, nwih1};
  ca.d[2] = {W_hh1, whh1, nwhh1};
  ca.d[3] = {W_ih2, wih2, nwih2};
  ca.d[4] = {W_hh2, whh2, nwhh2};
  ca.d[5] = {W_ih3, wih3, nwih3};
  ca.d[6] = {W_hh3, whh3, nwhh3};
  cast_many<<<1024, 256, 0, stream>>>(ca);

  // per-layer chunk length: largest TC (pow2, >=16) whose xg buffer fits
  auto pick_tc = [&](int NO, int XD) -> int {
    for (int tc = T; tc >= 32; tc >>= 1) {
      size_t need = (size_t)(B / 16) * tc * NO * 16 * 2   // tiles
                  + (size_t)XD * NO * 16 * 2 + 256;       // prefetch-overrun pad
      if (need <= avail) return tc;
    }
    return 16;
  };

  // LDS: rec1 keeps n-gate Whh in LDS; rec2/rec3 only double-buffered h
  constexpr int SM1 = (H1 + 2 * 16) * (H1 + 8) * 2;  // 152064
  constexpr int SM2 = (2 * 16) * (H2 + 8) * 2;       // 8704
  constexpr int SM3 = (2 * 16) * (H3 + 8) * 2;       // 4608

  auto* r1 = gru_rec<H1, 8, 2, true,  true,  2>;
  auto* r2 = gru_rec<H2, 8, 1, false, true,  4>;
  auto* r3 = gru_rec<H3, 4, 1, false, false, 4>;
  (void)hipFuncSetAttribute((const void*)r1, hipFuncAttributeMaxDynamicSharedMemorySize, SM1);

  // ---- layer 1 ----
  {
    const int TC = pick_tc(3 * H1, 2);
    for (int t0 = 0; t0 < T; t0 += TC) {
      xg_gemm<F, 3 * H1, 4, 12><<<dim3(B / 16, TC / 16), 4 * 64, 0, stream>>>(
          xh, wih1, b_ih1, xgbuf, t0, TC);
      r1<<<B / 16, 8 * 64, SM1, stream>>>(xgbuf, whh1, b_hh1, h1, hstate, t0, t0 + TC, TC);
    }
  }
  // ---- layer 2 ----
  {
    const int TC = pick_tc(3 * H2, 4);
    for (int t0 = 0; t0 < T; t0 += TC) {
      xg_gemm<H1, 3 * H2, 8, 3><<<dim3(B / 16, TC / 16), 8 * 64, 0, stream>>>(
          h1, wih2, b_ih2, xgbuf, t0, TC);
      r2<<<B / 16, 8 * 64, SM2, stream>>>(xgbuf, whh2, b_hh2, h2, hstate, t0, t0 + TC, TC);
    }
  }
  // ---- layer 3 ----
  {
    const int TC = pick_tc(3 * H3, 4);
    for (int t0 = 0; t0 < T; t0 += TC) {
      xg_gemm<H2, 3 * H3, 4, 3><<<dim3(B / 16, TC / 16), 4 * 64, 0, stream>>>(
          h2, wih3, b_ih3, xgbuf, t0, TC);
      r3<<<B / 16, 4 * 64, SM3, stream>>>(xgbuf, whh3, b_hh3, nullptr, hstate, t0, t0 + TC, TC);
    }
  }

  dense_kernel<<<B / 64, 64, 0, stream>>>(hstate, W_d, b_d, out);
}